// Round 2
// baseline (1185.931 us; speedup 1.0000x reference)
//
#include <hip/hip_runtime.h>

// Batched Jacobi diffusion, B=8, 128x128, iters=1000.
// One block (512 threads) per batch on one CU. Each thread owns an 8x4
// register tile (32 cells); all interior neighbors are register-resident.
// Only tile-boundary values are exchanged, via compact double-buffered LDS
// arrays laid out so every access is a conflict-free ds_read/write_b128:
//   TopRow[ty][c], BotRow[ty][c]  : horizontal rows, stride 132
//   Lcol[tx][r],  Rcol[tx][r]     : boundary columns stored transposed
// One __syncthreads per iteration (double buffer).

#define GH 128
#define GW 128
#define TW 8     // tile width  (cells per thread in x)
#define TH 4     // tile height (cells per thread in y)
#define NTX 16   // threads in x
#define NTY 32   // threads in y
#define NT  (NTX * NTY)            // 512
#define SROW 132                   // padded stride (breaks bank alignment)
#define TOPO 0
#define BOTO (32 * SROW)
#define LCO  (64 * SROW)
#define RCO  (80 * SROW)
#define SETW (96 * SROW)           // words per buffer set

__global__ __launch_bounds__(NT, 2) void jacobi_flux_kernel(
    const float* __restrict__ k_all,
    const int* __restrict__ iters_p,
    float* __restrict__ out)
{
    __shared__ __align__(16) float sh[2 * SETW];   // ~99 KB

    const int b   = blockIdx.x;
    const int tid = threadIdx.x;
    const int tx  = tid & (NTX - 1);
    const int ty  = tid >> 4;
    const int C0  = tx * TW;
    const int R0  = ty * TH;
    const float* kb = k_all + b * GH * GW;
    const int iters = *iters_p;

    // ---- normalized face conductivities (one-time, global reads, clamped) ----
    float rN[TH][TW], rS[TH][TW], rWc[TH][TW], rEc[TH][TW];
    #pragma unroll
    for (int i = 0; i < TH; ++i) {
        const int r  = R0 + i;
        const int ru = (r == 0)      ? 0      : r - 1;
        const int rd = (r == GH - 1) ? GH - 1 : r + 1;
        #pragma unroll
        for (int j = 0; j < TW; ++j) {
            const int c  = C0 + j;
            const int cl = (c == 0)      ? 0      : c - 1;
            const int cr = (c == GW - 1) ? GW - 1 : c + 1;
            float kc = kb[r * GW + c];
            float kn = 0.5f * (kc + kb[ru * GW + c]);
            float ks = 0.5f * (kc + kb[rd * GW + c]);
            float kw = 0.5f * (kc + kb[r * GW + cl]);
            float ke = 0.5f * (kc + kb[r * GW + cr]);
            float inv = 1.0f / (kn + ks + kw + ke);
            rN[i][j]  = kn * inv;
            rS[i][j]  = ks * inv;
            rWc[i][j] = kw * inv;
            rEc[i][j] = ke * inv;
        }
    }

    // ---- boundary-exchange addresses (word offsets within a buffer set) ----
    const int topW = TOPO + ty * SROW + C0;            // publish my top row
    const int botW = BOTO + ty * SROW + C0;            // publish my bottom row
    const int lW   = LCO  + tx * SROW + R0;            // publish my left col
    const int rW   = RCO  + tx * SROW + R0;            // publish my right col
    const int upR  = BOTO + ((ty == 0)       ? 0       : ty - 1) * SROW + C0;
    const int dnR  = TOPO + ((ty == NTY - 1) ? NTY - 1 : ty + 1) * SROW + C0;
    const int lfR  = (tx == 0)       ? (LCO + R0)                        // edge: own col 0
                                     : (RCO + (tx - 1) * SROW + R0);
    const int rtR  = (tx == NTX - 1) ? (RCO + (NTX - 1) * SROW + R0)     // edge: own col 127
                                     : (LCO + (tx + 1) * SROW + R0);

    auto publish = [&](float* W, float (&t)[TH][TW]) {
        *(float4*)(W + topW)     = make_float4(t[0][0], t[0][1], t[0][2], t[0][3]);
        *(float4*)(W + topW + 4) = make_float4(t[0][4], t[0][5], t[0][6], t[0][7]);
        *(float4*)(W + botW)     = make_float4(t[TH-1][0], t[TH-1][1], t[TH-1][2], t[TH-1][3]);
        *(float4*)(W + botW + 4) = make_float4(t[TH-1][4], t[TH-1][5], t[TH-1][6], t[TH-1][7]);
        *(float4*)(W + lW)       = make_float4(t[0][0], t[1][0], t[2][0], t[3][0]);
        *(float4*)(W + rW)       = make_float4(t[0][TW-1], t[1][TW-1], t[2][TW-1], t[3][TW-1]);
    };

    // ---- init T: zeros, grid row 0 = 1 ----
    float cur[TH][TW];
    #pragma unroll
    for (int i = 0; i < TH; ++i)
        #pragma unroll
        for (int j = 0; j < TW; ++j)
            cur[i][j] = (R0 + i == 0) ? 1.0f : 0.0f;

    publish(sh, cur);          // set 0 holds initial boundaries
    __syncthreads();

    // ---- main loop: 1 barrier per iteration ----
    int p = 0;                 // read set p, write set 1-p
    for (int it = 0; it < iters; ++it) {
        const float* Rb = sh + p * SETW;
        float*       Wb = sh + (1 - p) * SETW;

        float4 u0 = *(const float4*)(Rb + upR);
        float4 u1 = *(const float4*)(Rb + upR + 4);
        float4 d0 = *(const float4*)(Rb + dnR);
        float4 d1 = *(const float4*)(Rb + dnR + 4);
        float4 lv = *(const float4*)(Rb + lfR);
        float4 rv = *(const float4*)(Rb + rtR);
        float upH[TW] = {u0.x, u0.y, u0.z, u0.w, u1.x, u1.y, u1.z, u1.w};
        float dnH[TW] = {d0.x, d0.y, d0.z, d0.w, d1.x, d1.y, d1.z, d1.w};
        float lfH[TH] = {lv.x, lv.y, lv.z, lv.w};
        float rtH[TH] = {rv.x, rv.y, rv.z, rv.w};

        float nw[TH][TW];
        #pragma unroll
        for (int i = 0; i < TH; ++i) {
            #pragma unroll
            for (int j = 0; j < TW; ++j) {
                float up = (i == 0)      ? upH[j] : cur[i - 1][j];
                float dn = (i == TH - 1) ? dnH[j] : cur[i + 1][j];
                float lf = (j == 0)      ? lfH[i] : cur[i][j - 1];
                float rt = (j == TW - 1) ? rtH[i] : cur[i][j + 1];
                nw[i][j] = rN[i][j] * up + rS[i][j] * dn
                         + rWc[i][j] * lf + rEc[i][j] * rt;
            }
        }
        if (ty == 0) {
            #pragma unroll
            for (int j = 0; j < TW; ++j) nw[0][j] = 1.0f;       // Dirichlet top
        }
        if (ty == NTY - 1) {
            #pragma unroll
            for (int j = 0; j < TW; ++j) nw[TH - 1][j] = 0.0f;  // Dirichlet bottom
        }
        #pragma unroll
        for (int i = 0; i < TH; ++i)
            #pragma unroll
            for (int j = 0; j < TW; ++j)
                cur[i][j] = nw[i][j];

        publish(Wb, cur);
        p ^= 1;
        __syncthreads();
    }

    // ---- flux: Jy row 64 = -k[64]*(T[65]-T[64]); kappa = sum over columns ----
    // ty==16 owns rows 64..67: cur[0]=row64, cur[1]=row65
    float partial = 0.0f;
    if (ty == 16) {
        #pragma unroll
        for (int j = 0; j < TW; ++j)
            partial -= kb[64 * GW + C0 + j] * (cur[1][j] - cur[0][j]);
    }
    __syncthreads();
    if (ty == 16) sh[tx] = partial;
    __syncthreads();
    if (tid == 0) {
        float s = 0.0f;
        #pragma unroll
        for (int i = 0; i < NTX; ++i) s += sh[i];
        out[b] = s;
    }
}

extern "C" void kernel_launch(void* const* d_in, const int* in_sizes, int n_in,
                              void* d_out, int out_size, void* d_ws, size_t ws_size,
                              hipStream_t stream)
{
    const float* k     = (const float*)d_in[0];
    const int*   iters = (const int*)d_in[1];
    float*       out   = (float*)d_out;
    jacobi_flux_kernel<<<dim3(8), dim3(NT), 0, stream>>>(k, iters, out);
}

// Round 3
// 988.080 us; speedup vs baseline: 1.2002x; 1.2002x over previous
//
#include <hip/hip_runtime.h>

// Batched Jacobi diffusion, B=8, 128x128, iters=1000. One 512-thread block
// per batch. 16 half-wave groups (32 lanes) each own 8 full grid rows; each
// lane owns 4 adjacent columns x 8 rows in registers.
//  - vertical interior neighbors: registers
//  - horizontal neighbors: ds_bpermute lane+-1 (VALU-pipe-free crossbar, no
//    barrier), half-wave seams align with grid-edge clamps
//  - strip top/bottom rows: dense double-buffered LDS rows (b128, 0-conflict),
//    ONE __syncthreads per iteration.

#define GH 128
#define GW 128
#define NGROUP 16          // half-wave groups per block
#define ROWS 8             // rows per group
#define COLS 4             // cols per lane
#define NT 512

__global__ __launch_bounds__(NT, 2) void jacobi_flux_kernel(
    const float* __restrict__ k_all,
    const int* __restrict__ iters_p,
    float* __restrict__ out)
{
    // halo rows: [set][group][col]  (dense 128-float rows, 16B-aligned)
    __shared__ __align__(16) float sTop[2][NGROUP][GW];
    __shared__ __align__(16) float sBot[2][NGROUP][GW];

    const int b    = blockIdx.x;
    const int tid  = threadIdx.x;
    const int l    = tid & 31;          // lane within group
    const int g    = tid >> 5;          // group 0..15
    const int C0   = l * COLS;          // first owned column
    const int R0   = g * ROWS;          // first owned row
    const float* kb = k_all + b * GH * GW;
    const int iters = *iters_p;

    // bpermute byte-addresses for lane+-1 across the full wave (seams clamped)
    const int lane64 = tid & 63;
    const int idxL = (lane64 - 1) << 2;
    const int idxR = (lane64 + 1) << 2;
    const bool edgeL = (l == 0);        // my c0 is grid col 0
    const bool edgeR = (l == 31);       // my c3 is grid col 127

    // ---- one-time: normalized face conductivities (32 cells -> 128 VGPRs) ----
    float rN[ROWS][COLS], rS[ROWS][COLS], rW[ROWS][COLS], rE[ROWS][COLS];
    #pragma unroll
    for (int i = 0; i < ROWS; ++i) {
        const int r  = R0 + i;
        const int ru = (r == 0)      ? 0      : r - 1;
        const int rd = (r == GH - 1) ? GH - 1 : r + 1;
        #pragma unroll
        for (int j = 0; j < COLS; ++j) {
            const int c  = C0 + j;
            const int cl = (c == 0)      ? 0      : c - 1;
            const int cr = (c == GW - 1) ? GW - 1 : c + 1;
            float kc = kb[r * GW + c];
            float kn = 0.5f * (kc + kb[ru * GW + c]);
            float ks = 0.5f * (kc + kb[rd * GW + c]);
            float kw = 0.5f * (kc + kb[r * GW + cl]);
            float ke = 0.5f * (kc + kb[r * GW + cr]);
            float inv = 1.0f / (kn + ks + kw + ke);
            rN[i][j] = kn * inv;  rS[i][j] = ks * inv;
            rW[i][j] = kw * inv;  rE[i][j] = ke * inv;
        }
    }

    // ---- init T: zeros, grid row 0 = 1 ----
    float cur[ROWS][COLS];
    #pragma unroll
    for (int i = 0; i < ROWS; ++i)
        #pragma unroll
        for (int j = 0; j < COLS; ++j)
            cur[i][j] = (R0 + i == 0) ? 1.0f : 0.0f;

    // publish initial halo rows into set 0
    *(float4*)&sTop[0][g][C0] = *(float4*)&cur[0][0];
    *(float4*)&sBot[0][g][C0] = *(float4*)&cur[ROWS - 1][0];
    __syncthreads();

    const int gUp = (g == 0)          ? 0          : g - 1;
    const int gDn = (g == NGROUP - 1) ? NGROUP - 1 : g + 1;

    int p = 0;
    for (int it = 0; it < iters; ++it) {
        // strip halos from current set (issued early, independent)
        float4 hu = *(const float4*)&sBot[p][gUp][C0];  // row R0-1
        float4 hd = *(const float4*)&sTop[p][gDn][C0];  // row R0+8
        float haloUp[COLS] = {hu.x, hu.y, hu.z, hu.w};
        float haloDn[COLS] = {hd.x, hd.y, hd.z, hd.w};

        // horizontal neighbor exchange: 2 bpermutes per row, on OLD values
        float lfv[ROWS], rtv[ROWS];
        #pragma unroll
        for (int i = 0; i < ROWS; ++i) {
            float fromL = __int_as_float(
                __builtin_amdgcn_ds_bpermute(idxL, __float_as_int(cur[i][COLS - 1])));
            float fromR = __int_as_float(
                __builtin_amdgcn_ds_bpermute(idxR, __float_as_int(cur[i][0])));
            lfv[i] = edgeL ? cur[i][0]        : fromL;   // clamp at col 0
            rtv[i] = edgeR ? cur[i][COLS - 1] : fromR;   // clamp at col 127
        }

        float nw[ROWS][COLS];
        #pragma unroll
        for (int i = 0; i < ROWS; ++i) {
            #pragma unroll
            for (int j = 0; j < COLS; ++j) {
                float up = (i == 0)        ? haloUp[j] : cur[i - 1][j];
                float dn = (i == ROWS - 1) ? haloDn[j] : cur[i + 1][j];
                float lf = (j == 0)        ? lfv[i]    : cur[i][j - 1];
                float rt = (j == COLS - 1) ? rtv[i]    : cur[i][j + 1];
                nw[i][j] = fmaf(rN[i][j], up,
                           fmaf(rS[i][j], dn,
                           fmaf(rW[i][j], lf, rE[i][j] * rt)));
            }
        }
        // Dirichlet rows (only waves 0 and 7 diverge here, cheap)
        if (g == 0) {
            #pragma unroll
            for (int j = 0; j < COLS; ++j) nw[0][j] = 1.0f;
        }
        if (g == NGROUP - 1) {
            #pragma unroll
            for (int j = 0; j < COLS; ++j) nw[ROWS - 1][j] = 0.0f;
        }
        #pragma unroll
        for (int i = 0; i < ROWS; ++i)
            #pragma unroll
            for (int j = 0; j < COLS; ++j)
                cur[i][j] = nw[i][j];

        // publish my boundary rows into the other set
        *(float4*)&sTop[p ^ 1][g][C0] = *(float4*)&cur[0][0];
        *(float4*)&sBot[p ^ 1][g][C0] = *(float4*)&cur[ROWS - 1][0];
        p ^= 1;
        __syncthreads();
    }

    // ---- flux at row 64: group 8 holds rows 64..71 (cur[0],cur[1]) ----
    if (g == 8) {
        float partial = 0.0f;
        #pragma unroll
        for (int j = 0; j < COLS; ++j)
            partial -= kb[64 * GW + C0 + j] * (cur[1][j] - cur[0][j]);
        // reduce across lanes 0..31 of this wave
        #pragma unroll
        for (int off = 16; off > 0; off >>= 1)
            partial += __shfl_down(partial, off, 64);
        if (l == 0) out[b] = partial;
    }
}

extern "C" void kernel_launch(void* const* d_in, const int* in_sizes, int n_in,
                              void* d_out, int out_size, void* d_ws, size_t ws_size,
                              hipStream_t stream)
{
    const float* k     = (const float*)d_in[0];
    const int*   iters = (const int*)d_in[1];
    float*       out   = (float*)d_out;
    jacobi_flux_kernel<<<dim3(8), dim3(NT), 0, stream>>>(k, iters, out);
}

// Round 4
// 932.885 us; speedup vs baseline: 1.2713x; 1.0592x over previous
//
#include <hip/hip_runtime.h>

// Batched Jacobi diffusion, B=8, 128x128, iters=1000. One 1024-thread block
// per batch (16 waves/CU = 4/SIMD for latency hiding). 32 half-wave groups
// (32 lanes) each own 4 grid rows; each lane owns 4 adjacent cols x 4 rows.
//  - vertical interior neighbors: registers
//  - horizontal neighbors: ds_bpermute lane+-1 (half-wave seams align with
//    grid-edge clamps)
//  - strip top/bottom rows: dense double-buffered LDS rows, 1 barrier/iter.
// Register budget: 64 coeff + 16 cur + temps ~= 112 VGPR -> fits 128-cap at
// 4 waves/SIMD (avoids the round-3 AGPR shuttle that inflated VALU issue).

#define GH 128
#define GW 128
#define NGROUP 32          // half-wave groups per block
#define ROWS 4             // rows per group
#define COLS 4             // cols per lane
#define NT 1024

__global__ __launch_bounds__(NT, 4) void jacobi_flux_kernel(
    const float* __restrict__ k_all,
    const int* __restrict__ iters_p,
    float* __restrict__ out)
{
    // halo rows: [set][group][col]  (dense 128-float rows, 16B-aligned)
    __shared__ __align__(16) float sTop[2][NGROUP][GW];   // 32 KB
    __shared__ __align__(16) float sBot[2][NGROUP][GW];   // 32 KB

    const int b    = blockIdx.x;
    const int tid  = threadIdx.x;
    const int l    = tid & 31;          // lane within group
    const int g    = tid >> 5;          // group 0..31
    const int C0   = l * COLS;          // first owned column
    const int R0   = g * ROWS;          // first owned row
    const float* kb = k_all + b * GH * GW;
    const int iters = *iters_p;

    // bpermute byte-addresses for lane+-1 (within full wave; seams clamped)
    const int lane64 = tid & 63;
    const int idxL = (lane64 - 1) << 2;
    const int idxR = (lane64 + 1) << 2;
    const bool edgeL = (l == 0);        // my c0 is grid col 0
    const bool edgeR = (l == 31);       // my c3 is grid col 127

    // ---- one-time: normalized face conductivities (16 cells -> 64 VGPRs) ----
    float rN[ROWS][COLS], rS[ROWS][COLS], rW[ROWS][COLS], rE[ROWS][COLS];
    #pragma unroll
    for (int i = 0; i < ROWS; ++i) {
        const int r  = R0 + i;
        const int ru = (r == 0)      ? 0      : r - 1;
        const int rd = (r == GH - 1) ? GH - 1 : r + 1;
        #pragma unroll
        for (int j = 0; j < COLS; ++j) {
            const int c  = C0 + j;
            const int cl = (c == 0)      ? 0      : c - 1;
            const int cr = (c == GW - 1) ? GW - 1 : c + 1;
            float kc = kb[r * GW + c];
            float kn = 0.5f * (kc + kb[ru * GW + c]);
            float ks = 0.5f * (kc + kb[rd * GW + c]);
            float kw = 0.5f * (kc + kb[r * GW + cl]);
            float ke = 0.5f * (kc + kb[r * GW + cr]);
            float inv = 1.0f / (kn + ks + kw + ke);
            rN[i][j] = kn * inv;  rS[i][j] = ks * inv;
            rW[i][j] = kw * inv;  rE[i][j] = ke * inv;
        }
    }

    // ---- init T: zeros, grid row 0 = 1 ----
    float cur[ROWS][COLS];
    #pragma unroll
    for (int i = 0; i < ROWS; ++i)
        #pragma unroll
        for (int j = 0; j < COLS; ++j)
            cur[i][j] = (R0 + i == 0) ? 1.0f : 0.0f;

    // publish initial halo rows into set 0
    *(float4*)&sTop[0][g][C0] = *(float4*)&cur[0][0];
    *(float4*)&sBot[0][g][C0] = *(float4*)&cur[ROWS - 1][0];
    __syncthreads();

    const int gUp = (g == 0)          ? 0          : g - 1;
    const int gDn = (g == NGROUP - 1) ? NGROUP - 1 : g + 1;

    int p = 0;
    for (int it = 0; it < iters; ++it) {
        // strip halos from current set (independent, issued early)
        float4 hu = *(const float4*)&sBot[p][gUp][C0];  // row R0-1
        float4 hd = *(const float4*)&sTop[p][gDn][C0];  // row R0+ROWS
        float haloUp[COLS] = {hu.x, hu.y, hu.z, hu.w};
        float haloDn[COLS] = {hd.x, hd.y, hd.z, hd.w};

        // horizontal neighbor exchange: 2 bpermutes per row, on OLD values
        float lfv[ROWS], rtv[ROWS];
        #pragma unroll
        for (int i = 0; i < ROWS; ++i) {
            float fromL = __int_as_float(
                __builtin_amdgcn_ds_bpermute(idxL, __float_as_int(cur[i][COLS - 1])));
            float fromR = __int_as_float(
                __builtin_amdgcn_ds_bpermute(idxR, __float_as_int(cur[i][0])));
            lfv[i] = edgeL ? cur[i][0]        : fromL;   // clamp at col 0
            rtv[i] = edgeR ? cur[i][COLS - 1] : fromR;   // clamp at col 127
        }

        float nw[ROWS][COLS];
        #pragma unroll
        for (int i = 0; i < ROWS; ++i) {
            #pragma unroll
            for (int j = 0; j < COLS; ++j) {
                float up = (i == 0)        ? haloUp[j] : cur[i - 1][j];
                float dn = (i == ROWS - 1) ? haloDn[j] : cur[i + 1][j];
                float lf = (j == 0)        ? lfv[i]    : cur[i][j - 1];
                float rt = (j == COLS - 1) ? rtv[i]    : cur[i][j + 1];
                nw[i][j] = fmaf(rN[i][j], up,
                           fmaf(rS[i][j], dn,
                           fmaf(rW[i][j], lf, rE[i][j] * rt)));
            }
        }
        if (g == 0) {
            #pragma unroll
            for (int j = 0; j < COLS; ++j) nw[0][j] = 1.0f;        // Dirichlet top
        }
        if (g == NGROUP - 1) {
            #pragma unroll
            for (int j = 0; j < COLS; ++j) nw[ROWS - 1][j] = 0.0f; // Dirichlet bottom
        }
        #pragma unroll
        for (int i = 0; i < ROWS; ++i)
            #pragma unroll
            for (int j = 0; j < COLS; ++j)
                cur[i][j] = nw[i][j];

        // publish my boundary rows into the other set
        *(float4*)&sTop[p ^ 1][g][C0] = *(float4*)&cur[0][0];
        *(float4*)&sBot[p ^ 1][g][C0] = *(float4*)&cur[ROWS - 1][0];
        p ^= 1;
        __syncthreads();
    }

    // ---- flux at row 64: group 16 holds rows 64..67 (cur[0]=r64, cur[1]=r65) ----
    if (g == 16) {
        float partial = 0.0f;
        #pragma unroll
        for (int j = 0; j < COLS; ++j)
            partial -= kb[64 * GW + C0 + j] * (cur[1][j] - cur[0][j]);
        // reduce across the 32 lanes of this half-wave (width=32 partitions)
        #pragma unroll
        for (int off = 16; off > 0; off >>= 1)
            partial += __shfl_down(partial, off, 32);
        if (l == 0) out[b] = partial;
    }
}

extern "C" void kernel_launch(void* const* d_in, const int* in_sizes, int n_in,
                              void* d_out, int out_size, void* d_ws, size_t ws_size,
                              hipStream_t stream)
{
    const float* k     = (const float*)d_in[0];
    const int*   iters = (const int*)d_in[1];
    float*       out   = (float*)d_out;
    jacobi_flux_kernel<<<dim3(8), dim3(NT), 0, stream>>>(k, iters, out);
}

// Round 5
// 851.922 us; speedup vs baseline: 1.3921x; 1.0950x over previous
//
#include <hip/hip_runtime.h>

// Batched Jacobi diffusion, B=8, 128x128, iters=1000. One 1024-thread block
// per batch. 32 half-wave groups x 4 rows; lane owns 4x4 cells.
// Phase-desynchronized iteration (round-5 restructure):
//   post-barrier: 2 ds_read_b128 halo reads + all FMA (reads hidden under
//                 interior-row FMAs; LDS pipe nearly idle)
//   pre-barrier:  8 ds_bpermute on the NEW values (own-wave data, needs no
//                 barrier) + 2 ds_write_b128 publishes
// plus 2x-unrolled register ping-pong (no cur=nw copy). 1 barrier/iter.

#define GH 128
#define GW 128
#define NGROUP 32
#define ROWS 4
#define COLS 4
#define NT 1024

__global__ __launch_bounds__(NT, 4) void jacobi_flux_kernel(
    const float* __restrict__ k_all,
    const int* __restrict__ iters_p,
    float* __restrict__ out)
{
    __shared__ __align__(16) float sTop[2][NGROUP][GW];   // 32 KB
    __shared__ __align__(16) float sBot[2][NGROUP][GW];   // 32 KB

    const int b   = blockIdx.x;
    const int tid = threadIdx.x;
    const int l   = tid & 31;
    const int g   = tid >> 5;
    const int C0  = l * COLS;
    const int R0  = g * ROWS;
    const float* kb = k_all + b * GH * GW;
    const int iters = *iters_p;

    const int lane64 = tid & 63;
    const int idxL = (lane64 - 1) << 2;
    const int idxR = (lane64 + 1) << 2;
    const bool edgeL = (l == 0);
    const bool edgeR = (l == 31);
    const int gUp = (g == 0)          ? 0          : g - 1;
    const int gDn = (g == NGROUP - 1) ? NGROUP - 1 : g + 1;
    const bool gTop = (g == 0);
    const bool gBot = (g == NGROUP - 1);

    // ---- one-time: normalized face conductivities ----
    float rN[ROWS][COLS], rS[ROWS][COLS], rW[ROWS][COLS], rE[ROWS][COLS];
    #pragma unroll
    for (int i = 0; i < ROWS; ++i) {
        const int r  = R0 + i;
        const int ru = (r == 0)      ? 0      : r - 1;
        const int rd = (r == GH - 1) ? GH - 1 : r + 1;
        #pragma unroll
        for (int j = 0; j < COLS; ++j) {
            const int c  = C0 + j;
            const int cl = (c == 0)      ? 0      : c - 1;
            const int cr = (c == GW - 1) ? GW - 1 : c + 1;
            float kc = kb[r * GW + c];
            float kn = 0.5f * (kc + kb[ru * GW + c]);
            float ks = 0.5f * (kc + kb[rd * GW + c]);
            float kw = 0.5f * (kc + kb[r * GW + cl]);
            float ke = 0.5f * (kc + kb[r * GW + cr]);
            float inv = 1.0f / (kn + ks + kw + ke);
            rN[i][j] = kn * inv;  rS[i][j] = ks * inv;
            rW[i][j] = kw * inv;  rE[i][j] = ke * inv;
        }
    }

    // ---- state: ping-pong register tiles ----
    float A[ROWS][COLS], B[ROWS][COLS];
    float lfA[ROWS], rtA[ROWS], lfB[ROWS], rtB[ROWS];

    #pragma unroll
    for (int i = 0; i < ROWS; ++i)
        #pragma unroll
        for (int j = 0; j < COLS; ++j)
            A[i][j] = (R0 + i == 0) ? 1.0f : 0.0f;

    // prime: publish A's boundary rows into set 0, horizontal neighbors of A
    sTop[0][g][C0+0] = A[0][0]; sTop[0][g][C0+1] = A[0][1];
    sTop[0][g][C0+2] = A[0][2]; sTop[0][g][C0+3] = A[0][3];
    sBot[0][g][C0+0] = A[ROWS-1][0]; sBot[0][g][C0+1] = A[ROWS-1][1];
    sBot[0][g][C0+2] = A[ROWS-1][2]; sBot[0][g][C0+3] = A[ROWS-1][3];
    #pragma unroll
    for (int i = 0; i < ROWS; ++i) {
        float fL = __int_as_float(__builtin_amdgcn_ds_bpermute(idxL, __float_as_int(A[i][COLS-1])));
        float fR = __int_as_float(__builtin_amdgcn_ds_bpermute(idxR, __float_as_int(A[i][0])));
        lfA[i] = edgeL ? A[i][0]        : fL;
        rtA[i] = edgeR ? A[i][COLS-1]   : fR;
    }
    __syncthreads();

    auto step = [&](const float (&src)[ROWS][COLS], float (&dst)[ROWS][COLS],
                    const float (&lfS)[ROWS], const float (&rtS)[ROWS],
                    float (&lfD)[ROWS], float (&rtD)[ROWS],
                    int rp, int wp) {
        // halo reads issued first (latency hidden under interior FMAs)
        float4 hu = *(const float4*)&sBot[rp][gUp][C0];   // row R0-1
        float4 hd = *(const float4*)&sTop[rp][gDn][C0];   // row R0+ROWS

        // interior rows 1..ROWS-2: register-only
        #pragma unroll
        for (int i = 1; i < ROWS - 1; ++i) {
            #pragma unroll
            for (int j = 0; j < COLS; ++j) {
                float lf = (j == 0)        ? lfS[i] : src[i][j - 1];
                float rt = (j == COLS - 1) ? rtS[i] : src[i][j + 1];
                dst[i][j] = fmaf(rN[i][j], src[i - 1][j],
                            fmaf(rS[i][j], src[i + 1][j],
                            fmaf(rW[i][j], lf, rE[i][j] * rt)));
            }
        }
        // boundary rows (consume halo)
        float huA[COLS] = {hu.x, hu.y, hu.z, hu.w};
        float hdA[COLS] = {hd.x, hd.y, hd.z, hd.w};
        #pragma unroll
        for (int j = 0; j < COLS; ++j) {
            float lf0 = (j == 0)        ? lfS[0] : src[0][j - 1];
            float rt0 = (j == COLS - 1) ? rtS[0] : src[0][j + 1];
            dst[0][j] = fmaf(rN[0][j], huA[j],
                        fmaf(rS[0][j], src[1][j],
                        fmaf(rW[0][j], lf0, rE[0][j] * rt0)));
            float lf3 = (j == 0)        ? lfS[ROWS-1] : src[ROWS-1][j - 1];
            float rt3 = (j == COLS - 1) ? rtS[ROWS-1] : src[ROWS-1][j + 1];
            dst[ROWS-1][j] = fmaf(rN[ROWS-1][j], src[ROWS-2][j],
                             fmaf(rS[ROWS-1][j], hdA[j],
                             fmaf(rW[ROWS-1][j], lf3, rE[ROWS-1][j] * rt3)));
        }
        if (gTop) {
            #pragma unroll
            for (int j = 0; j < COLS; ++j) dst[0][j] = 1.0f;
        }
        if (gBot) {
            #pragma unroll
            for (int j = 0; j < COLS; ++j) dst[ROWS-1][j] = 0.0f;
        }
        // pre-barrier: next-iter horizontal neighbors (own-wave bpermute)
        #pragma unroll
        for (int i = 0; i < ROWS; ++i) {
            float fL = __int_as_float(__builtin_amdgcn_ds_bpermute(idxL, __float_as_int(dst[i][COLS-1])));
            float fR = __int_as_float(__builtin_amdgcn_ds_bpermute(idxR, __float_as_int(dst[i][0])));
            lfD[i] = edgeL ? dst[i][0]        : fL;
            rtD[i] = edgeR ? dst[i][COLS-1]   : fR;
        }
        // publish boundary rows
        *(float4*)&sTop[wp][g][C0] = make_float4(dst[0][0], dst[0][1], dst[0][2], dst[0][3]);
        *(float4*)&sBot[wp][g][C0] = make_float4(dst[ROWS-1][0], dst[ROWS-1][1], dst[ROWS-1][2], dst[ROWS-1][3]);
        __syncthreads();
    };

    const int nPairs = iters >> 1;
    for (int it = 0; it < nPairs; ++it) {
        step(A, B, lfA, rtA, lfB, rtB, 0, 1);
        step(B, A, lfB, rtB, lfA, rtA, 1, 0);
    }
    if (iters & 1) {
        step(A, B, lfA, rtA, lfB, rtB, 0, 1);
        #pragma unroll
        for (int i = 0; i < ROWS; ++i)
            #pragma unroll
            for (int j = 0; j < COLS; ++j)
                A[i][j] = B[i][j];
    }

    // ---- flux at row 64: group 16 holds rows 64..67 (A[0]=r64, A[1]=r65) ----
    if (g == 16) {
        float partial = 0.0f;
        #pragma unroll
        for (int j = 0; j < COLS; ++j)
            partial -= kb[64 * GW + C0 + j] * (A[1][j] - A[0][j]);
        #pragma unroll
        for (int off = 16; off > 0; off >>= 1)
            partial += __shfl_down(partial, off, 32);
        if (l == 0) out[b] = partial;
    }
}

extern "C" void kernel_launch(void* const* d_in, const int* in_sizes, int n_in,
                              void* d_out, int out_size, void* d_ws, size_t ws_size,
                              hipStream_t stream)
{
    const float* k     = (const float*)d_in[0];
    const int*   iters = (const int*)d_in[1];
    float*       out   = (float*)d_out;
    jacobi_flux_kernel<<<dim3(8), dim3(NT), 0, stream>>>(k, iters, out);
}

// Round 6
// 846.127 us; speedup vs baseline: 1.4016x; 1.0068x over previous
//
#include <hip/hip_runtime.h>

// Batched Jacobi diffusion, B=8, 128x128, iters=1000. One 1024-thread block
// per batch. 32 half-wave groups x 4 rows; lane owns 4x4 cells.
// Round 6: amdgpu_waves_per_eu(4,4) pins the register budget to 128/wave so
// the ~110 live floats (64 coeffs + 2x16 state + halos) stay in arch VGPRs.
// Round 5's 64-VGPR allocation parked the coefficients in AGPRs and paid
// ~64 v_accvgpr_read per thread-iteration (~45% of all VALU issue).
//   post-barrier: 2 ds_read_b128 halo reads + all FMA
//   pre-barrier:  8 ds_bpermute on NEW values + 2 ds_write_b128 publishes
// 1 barrier/iter, 2x-unrolled register ping-pong.

#define GH 128
#define GW 128
#define NGROUP 32
#define ROWS 4
#define COLS 4
#define NT 1024

__global__ void __launch_bounds__(NT)
__attribute__((amdgpu_waves_per_eu(4, 4)))
jacobi_flux_kernel(
    const float* __restrict__ k_all,
    const int* __restrict__ iters_p,
    float* __restrict__ out)
{
    __shared__ __align__(16) float sTop[2][NGROUP][GW];   // 32 KB
    __shared__ __align__(16) float sBot[2][NGROUP][GW];   // 32 KB

    const int b   = blockIdx.x;
    const int tid = threadIdx.x;
    const int l   = tid & 31;
    const int g   = tid >> 5;
    const int C0  = l * COLS;
    const int R0  = g * ROWS;
    const float* kb = k_all + b * GH * GW;
    const int iters = *iters_p;

    const int lane64 = tid & 63;
    const int idxL = (lane64 - 1) << 2;
    const int idxR = (lane64 + 1) << 2;
    const bool edgeL = (l == 0);
    const bool edgeR = (l == 31);
    const int gUp = (g == 0)          ? 0          : g - 1;
    const int gDn = (g == NGROUP - 1) ? NGROUP - 1 : g + 1;
    const bool gTop = (g == 0);
    const bool gBot = (g == NGROUP - 1);

    // ---- one-time: normalized face conductivities ----
    float rN[ROWS][COLS], rS[ROWS][COLS], rW[ROWS][COLS], rE[ROWS][COLS];
    #pragma unroll
    for (int i = 0; i < ROWS; ++i) {
        const int r  = R0 + i;
        const int ru = (r == 0)      ? 0      : r - 1;
        const int rd = (r == GH - 1) ? GH - 1 : r + 1;
        #pragma unroll
        for (int j = 0; j < COLS; ++j) {
            const int c  = C0 + j;
            const int cl = (c == 0)      ? 0      : c - 1;
            const int cr = (c == GW - 1) ? GW - 1 : c + 1;
            float kc = kb[r * GW + c];
            float kn = 0.5f * (kc + kb[ru * GW + c]);
            float ks = 0.5f * (kc + kb[rd * GW + c]);
            float kw = 0.5f * (kc + kb[r * GW + cl]);
            float ke = 0.5f * (kc + kb[r * GW + cr]);
            float inv = 1.0f / (kn + ks + kw + ke);
            rN[i][j] = kn * inv;  rS[i][j] = ks * inv;
            rW[i][j] = kw * inv;  rE[i][j] = ke * inv;
        }
    }

    // ---- state: ping-pong register tiles ----
    float A[ROWS][COLS], B[ROWS][COLS];
    float lfA[ROWS], rtA[ROWS], lfB[ROWS], rtB[ROWS];

    #pragma unroll
    for (int i = 0; i < ROWS; ++i)
        #pragma unroll
        for (int j = 0; j < COLS; ++j)
            A[i][j] = (R0 + i == 0) ? 1.0f : 0.0f;

    // prime: publish A's boundary rows into set 0, horizontal neighbors of A
    *(float4*)&sTop[0][g][C0] = make_float4(A[0][0], A[0][1], A[0][2], A[0][3]);
    *(float4*)&sBot[0][g][C0] = make_float4(A[ROWS-1][0], A[ROWS-1][1], A[ROWS-1][2], A[ROWS-1][3]);
    #pragma unroll
    for (int i = 0; i < ROWS; ++i) {
        float fL = __int_as_float(__builtin_amdgcn_ds_bpermute(idxL, __float_as_int(A[i][COLS-1])));
        float fR = __int_as_float(__builtin_amdgcn_ds_bpermute(idxR, __float_as_int(A[i][0])));
        lfA[i] = edgeL ? A[i][0]        : fL;
        rtA[i] = edgeR ? A[i][COLS-1]   : fR;
    }
    __syncthreads();

    auto step = [&](const float (&src)[ROWS][COLS], float (&dst)[ROWS][COLS],
                    const float (&lfS)[ROWS], const float (&rtS)[ROWS],
                    float (&lfD)[ROWS], float (&rtD)[ROWS],
                    int rp, int wp) {
        // halo reads issued first (latency hidden under interior FMAs)
        float4 hu = *(const float4*)&sBot[rp][gUp][C0];   // row R0-1
        float4 hd = *(const float4*)&sTop[rp][gDn][C0];   // row R0+ROWS

        // interior rows 1..ROWS-2: register-only
        #pragma unroll
        for (int i = 1; i < ROWS - 1; ++i) {
            #pragma unroll
            for (int j = 0; j < COLS; ++j) {
                float lf = (j == 0)        ? lfS[i] : src[i][j - 1];
                float rt = (j == COLS - 1) ? rtS[i] : src[i][j + 1];
                dst[i][j] = fmaf(rN[i][j], src[i - 1][j],
                            fmaf(rS[i][j], src[i + 1][j],
                            fmaf(rW[i][j], lf, rE[i][j] * rt)));
            }
        }
        // boundary rows (consume halo)
        float huA[COLS] = {hu.x, hu.y, hu.z, hu.w};
        float hdA[COLS] = {hd.x, hd.y, hd.z, hd.w};
        #pragma unroll
        for (int j = 0; j < COLS; ++j) {
            float lf0 = (j == 0)        ? lfS[0] : src[0][j - 1];
            float rt0 = (j == COLS - 1) ? rtS[0] : src[0][j + 1];
            dst[0][j] = fmaf(rN[0][j], huA[j],
                        fmaf(rS[0][j], src[1][j],
                        fmaf(rW[0][j], lf0, rE[0][j] * rt0)));
            float lf3 = (j == 0)        ? lfS[ROWS-1] : src[ROWS-1][j - 1];
            float rt3 = (j == COLS - 1) ? rtS[ROWS-1] : src[ROWS-1][j + 1];
            dst[ROWS-1][j] = fmaf(rN[ROWS-1][j], src[ROWS-2][j],
                             fmaf(rS[ROWS-1][j], hdA[j],
                             fmaf(rW[ROWS-1][j], lf3, rE[ROWS-1][j] * rt3)));
        }
        if (gTop) {
            #pragma unroll
            for (int j = 0; j < COLS; ++j) dst[0][j] = 1.0f;
        }
        if (gBot) {
            #pragma unroll
            for (int j = 0; j < COLS; ++j) dst[ROWS-1][j] = 0.0f;
        }
        // pre-barrier: next-iter horizontal neighbors (own-wave bpermute)
        #pragma unroll
        for (int i = 0; i < ROWS; ++i) {
            float fL = __int_as_float(__builtin_amdgcn_ds_bpermute(idxL, __float_as_int(dst[i][COLS-1])));
            float fR = __int_as_float(__builtin_amdgcn_ds_bpermute(idxR, __float_as_int(dst[i][0])));
            lfD[i] = edgeL ? dst[i][0]        : fL;
            rtD[i] = edgeR ? dst[i][COLS-1]   : fR;
        }
        // publish boundary rows
        *(float4*)&sTop[wp][g][C0] = make_float4(dst[0][0], dst[0][1], dst[0][2], dst[0][3]);
        *(float4*)&sBot[wp][g][C0] = make_float4(dst[ROWS-1][0], dst[ROWS-1][1], dst[ROWS-1][2], dst[ROWS-1][3]);
        __syncthreads();
    };

    const int nPairs = iters >> 1;
    for (int it = 0; it < nPairs; ++it) {
        step(A, B, lfA, rtA, lfB, rtB, 0, 1);
        step(B, A, lfB, rtB, lfA, rtA, 1, 0);
    }
    if (iters & 1) {
        step(A, B, lfA, rtA, lfB, rtB, 0, 1);
        #pragma unroll
        for (int i = 0; i < ROWS; ++i)
            #pragma unroll
            for (int j = 0; j < COLS; ++j)
                A[i][j] = B[i][j];
    }

    // ---- flux at row 64: group 16 holds rows 64..67 (A[0]=r64, A[1]=r65) ----
    if (g == 16) {
        float partial = 0.0f;
        #pragma unroll
        for (int j = 0; j < COLS; ++j)
            partial -= kb[64 * GW + C0 + j] * (A[1][j] - A[0][j]);
        #pragma unroll
        for (int off = 16; off > 0; off >>= 1)
            partial += __shfl_down(partial, off, 32);
        if (l == 0) out[b] = partial;
    }
}

extern "C" void kernel_launch(void* const* d_in, const int* in_sizes, int n_in,
                              void* d_out, int out_size, void* d_ws, size_t ws_size,
                              hipStream_t stream)
{
    const float* k     = (const float*)d_in[0];
    const int*   iters = (const int*)d_in[1];
    float*       out   = (float*)d_out;
    jacobi_flux_kernel<<<dim3(8), dim3(NT), 0, stream>>>(k, iters, out);
}